// Round 3
// baseline (666.025 us; speedup 1.0000x reference)
//
#include <hip/hip_runtime.h>
#include <math.h>

// Problem constants
#define BATCH 128
#define CIN   3
#define DIN   16
#define HWIN  64
#define COUT  24
#define DOUT  14   // 16 - 3 + 1
#define HOUT  62   // 64 - 3 + 1
#define WOUT  62
#define HW2   (HWIN * HWIN)

// x:    [128][3][16][64][64]  fp32
// w:    [24][3][3][3][3]      fp32  (co, cin, kd, kh, kw)
// bias: [24]
// out:  [128][24][62][62]     fp32 softmax over channel dim
//
// v3: rolling depth accumulators. Block = (b, ho) row, 192 thr = 24 co x 8
// pixel-strips. Each staged depth-plane is read from LDS ONCE and feeds the
// three partial accumulators A0 (dz=d-2, tap kd=2), A1 (dz=d-1, kd=1),
// A2 (dz=d, kd=0). LDS reads: 27 instrs/plane vs 81/dz in v2 (2.6x less).
// Weights: volatile loads force all 81 into VGPRs once (v2 re-fetched them
// from global every dz -> VGPR_Count was 68).

template<bool KD0, bool KD1, bool KD2>
__device__ __forceinline__ void conv_step(const float* sxp, int wg,
                                          const float wreg[81],
                                          float A0[8], float A1[8], float A2[8])
{
    #pragma unroll
    for (int cin = 0; cin < 3; ++cin) {
        #pragma unroll
        for (int kh = 0; kh < 3; ++kh) {
            const float* rp = sxp + (cin * 3 + kh) * 68 + wg * 8;
            float xr[10];
            const float4 q0 = *(const float4*)(rp);
            const float4 q1 = *(const float4*)(rp + 4);
            const float2 q2 = *(const float2*)(rp + 8);
            xr[0] = q0.x; xr[1] = q0.y; xr[2] = q0.z; xr[3] = q0.w;
            xr[4] = q1.x; xr[5] = q1.y; xr[6] = q1.z; xr[7] = q1.w;
            xr[8] = q2.x; xr[9] = q2.y;
            #pragma unroll
            for (int kw = 0; kw < 3; ++kw) {
                if (KD2) {
                    const float wv = wreg[cin * 27 + 2 * 9 + kh * 3 + kw];
                    #pragma unroll
                    for (int i = 0; i < 8; ++i) A0[i] = fmaf(wv, xr[i + kw], A0[i]);
                }
                if (KD1) {
                    const float wv = wreg[cin * 27 + 1 * 9 + kh * 3 + kw];
                    #pragma unroll
                    for (int i = 0; i < 8; ++i) A1[i] = fmaf(wv, xr[i + kw], A1[i]);
                }
                if (KD0) {
                    const float wv = wreg[cin * 27 + 0 * 9 + kh * 3 + kw];
                    #pragma unroll
                    for (int i = 0; i < 8; ++i) A2[i] = fmaf(wv, xr[i + kw], A2[i]);
                }
            }
        }
    }
}

__global__ __launch_bounds__(192, 3) void conv_min_softmax_v3(
    const float* __restrict__ x,
    const float* __restrict__ w,
    const float* __restrict__ bias,
    float* __restrict__ out)
{
    __shared__ __align__(16) float sx[9 * 68];   // one depth plane: [cin*3+row][col(padded)]
    __shared__ __align__(16) float sm[COUT][68]; // pad 68: co*68%32 spreads banks, keeps 16B align

    const int tid = threadIdx.x;
    const int bid = blockIdx.x;          // 0 .. 128*62-1
    const int ho  = bid % HOUT;
    const int b   = bid / HOUT;

    const int co = tid >> 3;             // 0..23
    const int wg = tid & 7;              // 0..7 -> pixels wo = wg*8 .. wg*8+7

    const float* xb = x + (size_t)b * (CIN * DIN * HW2);

    // ---- weights: volatile forces exactly-once loads -> 81 live VGPRs ----
    float wreg[81];
    {
        volatile const float* wv = w + co * 81;
        #pragma unroll
        for (int q = 0; q < 81; ++q) wreg[q] = wv[q];
    }
    const float bco = bias[co];

    // staging decomposition: thread loads 3 elements/plane (one per cin)
    const int r  = tid >> 6;             // 0..2 input row within plane
    const int wc = tid & 63;             // 0..63 col

    float A0[8], A1[8], A2[8], m[8];
    #pragma unroll
    for (int i = 0; i < 8; ++i) { A0[i] = 0.f; A1[i] = 0.f; A2[i] = 0.f; m[i] = 1e30f; }

    // software-pipelined staging registers (plane d+1 loaded during step d)
    float g0, g1, g2, n0, n1, n2;
    g0 = xb[(0 * DIN + 0) * HW2 + (ho + r) * HWIN + wc];
    g1 = xb[(1 * DIN + 0) * HW2 + (ho + r) * HWIN + wc];
    g2 = xb[(2 * DIN + 0) * HW2 + (ho + r) * HWIN + wc];

#define STAGE_AND_PREFETCH(D)                                              \
    sx[(0 * 3 + r) * 68 + wc] = g0;                                        \
    sx[(1 * 3 + r) * 68 + wc] = g1;                                        \
    sx[(2 * 3 + r) * 68 + wc] = g2;                                        \
    if ((D) < DIN - 1) {                                                   \
        n0 = xb[(0 * DIN + (D) + 1) * HW2 + (ho + r) * HWIN + wc];         \
        n1 = xb[(1 * DIN + (D) + 1) * HW2 + (ho + r) * HWIN + wc];         \
        n2 = xb[(2 * DIN + (D) + 1) * HW2 + (ho + r) * HWIN + wc];         \
    }                                                                      \
    __syncthreads();

#define SHIFT()                                                            \
    _Pragma("unroll")                                                      \
    for (int i = 0; i < 8; ++i) { A0[i] = A1[i]; A1[i] = A2[i]; A2[i] = 0.f; } \
    g0 = n0; g1 = n1; g2 = n2;

    // d = 0: only kd=0 tap (target A2)
    STAGE_AND_PREFETCH(0)
    conv_step<true, false, false>(sx, wg, wreg, A0, A1, A2);
    SHIFT()
    __syncthreads();

    // d = 1: kd=0,1
    STAGE_AND_PREFETCH(1)
    conv_step<true, true, false>(sx, wg, wreg, A0, A1, A2);
    SHIFT()
    __syncthreads();

    // d = 2..13: all taps; finalize dz = d-2
    #pragma unroll 1
    for (int d = 2; d <= 13; ++d) {
        STAGE_AND_PREFETCH(d)
        conv_step<true, true, true>(sx, wg, wreg, A0, A1, A2);
        #pragma unroll
        for (int i = 0; i < 8; ++i) m[i] = fminf(m[i], A0[i]);
        SHIFT()
        __syncthreads();
    }

    // d = 14: kd=1,2; finalize dz=12
    STAGE_AND_PREFETCH(14)
    conv_step<false, true, true>(sx, wg, wreg, A0, A1, A2);
    #pragma unroll
    for (int i = 0; i < 8; ++i) m[i] = fminf(m[i], A0[i]);
    SHIFT()
    __syncthreads();

    // d = 15: kd=2 only; finalize dz=13
    STAGE_AND_PREFETCH(15)
    conv_step<false, false, true>(sx, wg, wreg, A0, A1, A2);
    #pragma unroll
    for (int i = 0; i < 8; ++i) m[i] = fminf(m[i], A0[i]);

#undef STAGE_AND_PREFETCH
#undef SHIFT

    // ---- epilogue: bias, then per-pixel softmax across the 24 channels ----
    #pragma unroll
    for (int i = 0; i < 8; ++i) sm[co][wg * 8 + i] = m[i] + bco;  // cols 62..67 junk/unused
    __syncthreads();

    if (tid < WOUT) {
        const int p = tid;
        float mx = -1e30f;
        #pragma unroll
        for (int c = 0; c < COUT; ++c) mx = fmaxf(mx, sm[c][p]);
        float e[COUT];
        float ssum = 0.f;
        #pragma unroll
        for (int c = 0; c < COUT; ++c) { e[c] = __expf(sm[c][p] - mx); ssum += e[c]; }
        const float inv = 1.f / ssum;
        float* ob = out + (size_t)b * COUT * (HOUT * WOUT) + ho * WOUT + p;
        #pragma unroll
        for (int c = 0; c < COUT; ++c) ob[(size_t)c * (HOUT * WOUT)] = e[c] * inv;
    }
}

extern "C" void kernel_launch(void* const* d_in, const int* in_sizes, int n_in,
                              void* d_out, int out_size, void* d_ws, size_t ws_size,
                              hipStream_t stream) {
    const float* x    = (const float*)d_in[0];
    const float* w    = (const float*)d_in[1];
    const float* bias = (const float*)d_in[2];
    float* out = (float*)d_out;

    const int blocks = BATCH * HOUT;     // 7936
    conv_min_softmax_v3<<<blocks, 192, 0, stream>>>(x, w, bias, out);
}